// Round 9
// baseline (3549.300 us; speedup 1.0000x reference)
//
#include <hip/hip_runtime.h>

// ChebNet: 3x ChebConv(K=5) + relu + linear head. N=100000, E=1600000, HID=64.
// R9: fused dense tail (mm234R: relu(ACC + T2@W2 + T3@W3 + T4@W4)), 4-edge
// vectorized fill, single memset. All-bf16 activations, fp32 accumulators.
// Gathers (8x ~85us) are at the 8-XCD compulsory L2-miss floor; counts at the
// fabric-atomic floor (~150us) -- both left as-is.

#define TB 256

typedef unsigned short u16;
typedef unsigned int u32;

__device__ inline u16 f2bf(float v) {            // RNE fp32 -> bf16
    unsigned u = __float_as_uint(v);
    return (u16)((u + 0x7fffu + ((u >> 16) & 1u)) >> 16);
}
__device__ inline float bflo(u32 v) { return __uint_as_float(v << 16); }
__device__ inline float bfhi(u32 v) { return __uint_as_float(v & 0xffff0000u); }
__device__ inline float bf2f(u16 v) { return __uint_as_float(((u32)v) << 16); }

// ---------- pass A: degree histograms + per-edge rank in dst bucket ----------
// At the device fabric-atomic latency*concurrency floor (~21 G atomics/s).
__global__ __launch_bounds__(TB) void k_counts(const int* __restrict__ src,
                                               const int* __restrict__ dst,
                                               int* __restrict__ cs,
                                               int* __restrict__ cdp,
                                               int* __restrict__ rank, int E) {
    int e = blockIdx.x * TB + threadIdx.x;
    if (e < E) {
        atomicAdd(&cs[src[e]], 1);
        rank[e] = atomicAdd(&cdp[(size_t)dst[e] * 16], 1);
    }
}

// ---------- CSR build ----------
__global__ __launch_bounds__(TB) void k_scan_a(const int* __restrict__ cdp,
                                               int* __restrict__ excl,
                                               int* __restrict__ bsum, int N) {
    __shared__ int s[TB];
    int t = threadIdx.x;
    int i = blockIdx.x * TB + t;
    int v = (i < N) ? cdp[(size_t)i * 16] : 0;
    s[t] = v;
    __syncthreads();
    for (int o = 1; o < TB; o <<= 1) {
        int add = (t >= o) ? s[t - o] : 0;
        __syncthreads();
        s[t] += add;
        __syncthreads();
    }
    if (i < N) excl[i] = s[t] - v;
    if (t == TB - 1) bsum[blockIdx.x] = s[t];
}

__global__ __launch_bounds__(1024) void k_scan_b(int* __restrict__ bsum, int nb) {
    __shared__ int s[1024];
    int t = threadIdx.x;
    int v = (t < nb) ? bsum[t] : 0;
    s[t] = v;
    __syncthreads();
    for (int o = 1; o < 1024; o <<= 1) {
        int add = (t >= o) ? s[t - o] : 0;
        __syncthreads();
        s[t] += add;
        __syncthreads();
    }
    if (t < nb) bsum[t] = s[t] - v;
}

__global__ __launch_bounds__(TB) void k_scan_c(int* __restrict__ rowptr,
                                               const int* __restrict__ bsum,
                                               const int* __restrict__ cs,
                                               float* __restrict__ dinv,
                                               int N, int E) {
    int i = blockIdx.x * TB + threadIdx.x;
    if (i < N) {
        rowptr[i] += bsum[blockIdx.x];
        int d = cs[i];
        dinv[i] = d > 0 ? rsqrtf((float)d) : 0.f;
    }
    if (i == 0) rowptr[N] = E;
}

// atomic-free fill, 4 edges/thread: pos = rowptr[dst] + rank
__global__ __launch_bounds__(TB) void k_fill(const int* __restrict__ src,
                                             const int* __restrict__ dst,
                                             const int* __restrict__ rank,
                                             const int* __restrict__ rowptr,
                                             const float* __restrict__ dinv,
                                             int2* __restrict__ csr, int E) {
    int t = blockIdx.x * TB + threadIdx.x;
    int e0 = t * 4;
    if (e0 + 3 < E) {
        int4 s = *(const int4*)(src + e0);
        int4 d = *(const int4*)(dst + e0);
        int4 r = *(const int4*)(rank + e0);
        csr[rowptr[d.x] + r.x] = make_int2(s.x, __float_as_int(-dinv[s.x] * dinv[d.x]));
        csr[rowptr[d.y] + r.y] = make_int2(s.y, __float_as_int(-dinv[s.y] * dinv[d.y]));
        csr[rowptr[d.z] + r.z] = make_int2(s.z, __float_as_int(-dinv[s.z] * dinv[d.z]));
        csr[rowptr[d.w] + r.w] = make_int2(s.w, __float_as_int(-dinv[s.w] * dinv[d.w]));
    } else {
        for (int e = e0; e < E; ++e) {
            int s = src[e], d = dst[e];
            csr[rowptr[d] + rank[e]] = make_int2(s, __float_as_int(-dinv[s] * dinv[d]));
        }
    }
}

// ---------- layer-1 (Fin=1) props: 16 lanes per node ----------
__global__ __launch_bounds__(TB) void k_gather1(const float* __restrict__ in,
                                                const float* __restrict__ prev,
                                                float* __restrict__ out,
                                                const int* __restrict__ rowptr,
                                                const int2* __restrict__ csr,
                                                float scale, float scale0, int N) {
    int l16 = threadIdx.x & 15;
    int n = blockIdx.x * (TB / 16) + (threadIdx.x >> 4);
    if (n >= N) return;
    int beg = rowptr[n], end = rowptr[n + 1];
    float s = 0.f;
    for (int i = beg + l16; i < end; i += 16) {
        int2 e = csr[i];
        s = fmaf(__int_as_float(e.y), in[e.x], s);
    }
    s += __shfl_down(s, 8, 16);
    s += __shfl_down(s, 4, 16);
    s += __shfl_down(s, 2, 16);
    s += __shfl_down(s, 1, 16);
    if (l16 == 0) out[n] = fmaf(scale, s, scale0 * prev[n]);
}

// Layer 1 combine: h = relu(b1 + sum_k t_k * W1[k]) -> bf16
__global__ __launch_bounds__(TB) void k_layer1(const float* __restrict__ x,
                                               const float* __restrict__ t1,
                                               const float* __restrict__ t2,
                                               const float* __restrict__ t3,
                                               const float* __restrict__ t4,
                                               const float* __restrict__ W1,
                                               const float* __restrict__ b1,
                                               u16* __restrict__ Hb, int N) {
    int tid = blockIdx.x * TB + threadIdx.x;
    if (tid >= N * 64) return;
    int n = tid >> 6, f = tid & 63;
    float v = b1[f];
    v = fmaf(x[n],  W1[f],       v);
    v = fmaf(t1[n], W1[64 + f],  v);
    v = fmaf(t2[n], W1[128 + f], v);
    v = fmaf(t3[n], W1[192 + f], v);
    v = fmaf(t4[n], W1[256 + f], v);
    Hb[tid] = f2bf(fmaxf(v, 0.f));
}

// ---------- prop: bf16 gather, 4-deep MLP (step-32, 4 slots/group) ----------
__global__ __launch_bounds__(TB) void k_gather64o(const u16* __restrict__ inb,
                                                  const u16* __restrict__ prevb,
                                                  u16* __restrict__ outB,
                                                  const int* __restrict__ rowptr,
                                                  const int2* __restrict__ csr,
                                                  float scale, float scale0, int N) {
    int lane = threadIdx.x & 63;
    int g = lane >> 3;
    int p = lane & 7;
    int n = blockIdx.x * (TB / 64) + (threadIdx.x >> 6);
    if (n >= N) return;
    int beg = rowptr[n], end = rowptr[n + 1];
    float s0 = 0.f, s1 = 0.f, s2 = 0.f, s3 = 0.f;
    float s4 = 0.f, s5 = 0.f, s6 = 0.f, s7 = 0.f;
    const u16* bp = inb + 8 * p;
    for (int i0 = beg; i0 < end; i0 += 32) {
        int ia = i0 + g, ib = ia + 8, ic = ia + 16, id = ia + 24;
        bool va = ia < end, vb = ib < end, vc = ic < end, vd = id < end;
        int2 ea = csr[va ? ia : beg];
        int2 eb = csr[vb ? ib : beg];
        int2 ec = csr[vc ? ic : beg];
        int2 ed = csr[vd ? id : beg];
        uint4 ra = *(const uint4*)(bp + (size_t)ea.x * 64);
        uint4 rb = *(const uint4*)(bp + (size_t)eb.x * 64);
        uint4 rc = *(const uint4*)(bp + (size_t)ec.x * 64);
        uint4 rd = *(const uint4*)(bp + (size_t)ed.x * 64);
        float wa = va ? __int_as_float(ea.y) : 0.f;
        float wb = vb ? __int_as_float(eb.y) : 0.f;
        float wc = vc ? __int_as_float(ec.y) : 0.f;
        float wd = vd ? __int_as_float(ed.y) : 0.f;
        s0 = fmaf(wa, bflo(ra.x), s0); s1 = fmaf(wa, bfhi(ra.x), s1);
        s2 = fmaf(wa, bflo(ra.y), s2); s3 = fmaf(wa, bfhi(ra.y), s3);
        s4 = fmaf(wa, bflo(ra.z), s4); s5 = fmaf(wa, bfhi(ra.z), s5);
        s6 = fmaf(wa, bflo(ra.w), s6); s7 = fmaf(wa, bfhi(ra.w), s7);
        s0 = fmaf(wb, bflo(rb.x), s0); s1 = fmaf(wb, bfhi(rb.x), s1);
        s2 = fmaf(wb, bflo(rb.y), s2); s3 = fmaf(wb, bfhi(rb.y), s3);
        s4 = fmaf(wb, bflo(rb.z), s4); s5 = fmaf(wb, bfhi(rb.z), s5);
        s6 = fmaf(wb, bflo(rb.w), s6); s7 = fmaf(wb, bfhi(rb.w), s7);
        s0 = fmaf(wc, bflo(rc.x), s0); s1 = fmaf(wc, bfhi(rc.x), s1);
        s2 = fmaf(wc, bflo(rc.y), s2); s3 = fmaf(wc, bfhi(rc.y), s3);
        s4 = fmaf(wc, bflo(rc.z), s4); s5 = fmaf(wc, bfhi(rc.z), s5);
        s6 = fmaf(wc, bflo(rc.w), s6); s7 = fmaf(wc, bfhi(rc.w), s7);
        s0 = fmaf(wd, bflo(rd.x), s0); s1 = fmaf(wd, bfhi(rd.x), s1);
        s2 = fmaf(wd, bflo(rd.y), s2); s3 = fmaf(wd, bfhi(rd.y), s3);
        s4 = fmaf(wd, bflo(rd.z), s4); s5 = fmaf(wd, bfhi(rd.z), s5);
        s6 = fmaf(wd, bflo(rd.w), s6); s7 = fmaf(wd, bfhi(rd.w), s7);
    }
#pragma unroll
    for (int o = 8; o < 64; o <<= 1) {
        s0 += __shfl_xor(s0, o, 64); s1 += __shfl_xor(s1, o, 64);
        s2 += __shfl_xor(s2, o, 64); s3 += __shfl_xor(s3, o, 64);
        s4 += __shfl_xor(s4, o, 64); s5 += __shfl_xor(s5, o, 64);
        s6 += __shfl_xor(s6, o, 64); s7 += __shfl_xor(s7, o, 64);
    }
    if (lane < 8) {
        size_t o = (size_t)n * 64 + 8 * p;
        float t0 = scale * s0, t1 = scale * s1, t2 = scale * s2, t3 = scale * s3;
        float t4 = scale * s4, t5 = scale * s5, t6 = scale * s6, t7 = scale * s7;
        if (scale0 != 0.f) {
            uint4 pv = *(const uint4*)(prevb + o);
            t0 = fmaf(scale0, bflo(pv.x), t0); t1 = fmaf(scale0, bfhi(pv.x), t1);
            t2 = fmaf(scale0, bflo(pv.y), t2); t3 = fmaf(scale0, bfhi(pv.y), t3);
            t4 = fmaf(scale0, bflo(pv.z), t4); t5 = fmaf(scale0, bfhi(pv.z), t5);
            t6 = fmaf(scale0, bflo(pv.w), t6); t7 = fmaf(scale0, bfhi(pv.w), t7);
        }
        uint4 b;
        b.x = ((u32)f2bf(t1) << 16) | (u32)f2bf(t0);
        b.y = ((u32)f2bf(t3) << 16) | (u32)f2bf(t2);
        b.z = ((u32)f2bf(t5) << 16) | (u32)f2bf(t4);
        b.w = ((u32)f2bf(t7) << 16) | (u32)f2bf(t6);
        *(uint4*)(outB + o) = b;
    }
}

// ---------- paired dense (bf16 inputs): acc = b + QA@Wa + QB@Wb ----------
__global__ __launch_bounds__(TB) void k_matmul2(const u16* __restrict__ QA,
                                                const u16* __restrict__ QB,
                                                const float* __restrict__ Wa,
                                                const float* __restrict__ Wb,
                                                const float* __restrict__ bias,
                                                float* __restrict__ acc, int N) {
    int lane = threadIdx.x & 63;
    int wid = blockIdx.x * (TB / 64) + (threadIdx.x >> 6);
    int nw = gridDim.x * (TB / 64);

    float wa[64], wb[64];
#pragma unroll
    for (int j = 0; j < 64; ++j) wa[j] = Wa[j * 64 + lane];
#pragma unroll
    for (int j = 0; j < 64; ++j) wb[j] = Wb[j * 64 + lane];
    float bv = bias[lane];

    for (int n = wid; n < N; n += nw) {
        size_t o = (size_t)n * 64;
        float a = bv;
        const uint4* ra = (const uint4*)(QA + o);
        const uint4* rb = (const uint4*)(QB + o);
#pragma unroll
        for (int j8 = 0; j8 < 8; ++j8) {
            uint4 r = ra[j8];
            a = fmaf(bflo(r.x), wa[8 * j8 + 0], a);
            a = fmaf(bfhi(r.x), wa[8 * j8 + 1], a);
            a = fmaf(bflo(r.y), wa[8 * j8 + 2], a);
            a = fmaf(bfhi(r.y), wa[8 * j8 + 3], a);
            a = fmaf(bflo(r.z), wa[8 * j8 + 4], a);
            a = fmaf(bfhi(r.z), wa[8 * j8 + 5], a);
            a = fmaf(bflo(r.w), wa[8 * j8 + 6], a);
            a = fmaf(bfhi(r.w), wa[8 * j8 + 7], a);
        }
#pragma unroll
        for (int j8 = 0; j8 < 8; ++j8) {
            uint4 r = rb[j8];
            a = fmaf(bflo(r.x), wb[8 * j8 + 0], a);
            a = fmaf(bfhi(r.x), wb[8 * j8 + 1], a);
            a = fmaf(bflo(r.y), wb[8 * j8 + 2], a);
            a = fmaf(bfhi(r.y), wb[8 * j8 + 3], a);
            a = fmaf(bflo(r.z), wb[8 * j8 + 4], a);
            a = fmaf(bfhi(r.z), wb[8 * j8 + 5], a);
            a = fmaf(bflo(r.w), wb[8 * j8 + 6], a);
            a = fmaf(bfhi(r.w), wb[8 * j8 + 7], a);
        }
        acc[o + lane] = a;
    }
}

// ---------- fused dense tail: h = relu(ACC + QA@Wa + QB@Wb + QC@Wc) -> bf16 ----------
// 3x64 register-resident W columns (~217 VGPR); 2 waves/EU floor.
__global__ __launch_bounds__(TB, 2) void k_matmul3R(const u16* __restrict__ QA,
                                                    const u16* __restrict__ QB,
                                                    const u16* __restrict__ QC,
                                                    const float* __restrict__ Wa,
                                                    const float* __restrict__ Wb,
                                                    const float* __restrict__ Wc,
                                                    const float* __restrict__ acc,
                                                    u16* __restrict__ hB, int N) {
    int lane = threadIdx.x & 63;
    int wid = blockIdx.x * (TB / 64) + (threadIdx.x >> 6);
    int nw = gridDim.x * (TB / 64);

    float wa[64], wb[64], wc[64];
#pragma unroll
    for (int j = 0; j < 64; ++j) wa[j] = Wa[j * 64 + lane];
#pragma unroll
    for (int j = 0; j < 64; ++j) wb[j] = Wb[j * 64 + lane];
#pragma unroll
    for (int j = 0; j < 64; ++j) wc[j] = Wc[j * 64 + lane];

    for (int n = wid; n < N; n += nw) {
        size_t o = (size_t)n * 64;
        float a = acc[o + lane];
        const uint4* ra = (const uint4*)(QA + o);
        const uint4* rb = (const uint4*)(QB + o);
        const uint4* rc = (const uint4*)(QC + o);
#pragma unroll
        for (int j8 = 0; j8 < 8; ++j8) {
            uint4 r = ra[j8];
            a = fmaf(bflo(r.x), wa[8 * j8 + 0], a);
            a = fmaf(bfhi(r.x), wa[8 * j8 + 1], a);
            a = fmaf(bflo(r.y), wa[8 * j8 + 2], a);
            a = fmaf(bfhi(r.y), wa[8 * j8 + 3], a);
            a = fmaf(bflo(r.z), wa[8 * j8 + 4], a);
            a = fmaf(bfhi(r.z), wa[8 * j8 + 5], a);
            a = fmaf(bflo(r.w), wa[8 * j8 + 6], a);
            a = fmaf(bfhi(r.w), wa[8 * j8 + 7], a);
        }
#pragma unroll
        for (int j8 = 0; j8 < 8; ++j8) {
            uint4 r = rb[j8];
            a = fmaf(bflo(r.x), wb[8 * j8 + 0], a);
            a = fmaf(bfhi(r.x), wb[8 * j8 + 1], a);
            a = fmaf(bflo(r.y), wb[8 * j8 + 2], a);
            a = fmaf(bfhi(r.y), wb[8 * j8 + 3], a);
            a = fmaf(bflo(r.z), wb[8 * j8 + 4], a);
            a = fmaf(bfhi(r.z), wb[8 * j8 + 5], a);
            a = fmaf(bflo(r.w), wb[8 * j8 + 6], a);
            a = fmaf(bfhi(r.w), wb[8 * j8 + 7], a);
        }
#pragma unroll
        for (int j8 = 0; j8 < 8; ++j8) {
            uint4 r = rc[j8];
            a = fmaf(bflo(r.x), wc[8 * j8 + 0], a);
            a = fmaf(bfhi(r.x), wc[8 * j8 + 1], a);
            a = fmaf(bflo(r.y), wc[8 * j8 + 2], a);
            a = fmaf(bfhi(r.y), wc[8 * j8 + 3], a);
            a = fmaf(bflo(r.z), wc[8 * j8 + 4], a);
            a = fmaf(bfhi(r.z), wc[8 * j8 + 5], a);
            a = fmaf(bflo(r.w), wc[8 * j8 + 6], a);
            a = fmaf(bfhi(r.w), wc[8 * j8 + 7], a);
        }
        hB[o + lane] = f2bf(fmaxf(a, 0.f));
    }
}

// ---------- final head: out = bfc + h @ Wfc (h bf16) ----------
__global__ __launch_bounds__(TB) void k_final(const u16* __restrict__ A,
                                              const float* __restrict__ Wfc,
                                              const float* __restrict__ bfc,
                                              float* __restrict__ out, int N) {
    int lane = threadIdx.x & 63;
    int wid = blockIdx.x * (TB / 64) + (threadIdx.x >> 6);
    if (wid >= N) return;
    float v = bf2f(A[(size_t)wid * 64 + lane]) * Wfc[lane];
#pragma unroll
    for (int o = 32; o > 0; o >>= 1) v += __shfl_down(v, o, 64);
    if (lane == 0) out[wid] = v + bfc[0];
}

extern "C" void kernel_launch(void* const* d_in, const int* in_sizes, int n_in,
                              void* d_out, int out_size, void* d_ws, size_t ws_size,
                              hipStream_t stream) {
    const float* x   = (const float*)d_in[0];
    const int*   ei  = (const int*)d_in[1];
    const float* W1  = (const float*)d_in[2];
    const float* b1  = (const float*)d_in[3];
    const float* W2  = (const float*)d_in[4];
    const float* b2  = (const float*)d_in[5];
    const float* W3  = (const float*)d_in[6];
    const float* b3  = (const float*)d_in[7];
    const float* Wfc = (const float*)d_in[8];
    const float* bfc = (const float*)d_in[9];
    float* out = (float*)d_out;

    const int N = in_sizes[0];
    const int E = in_sizes[1] / 2;
    const int* src = ei;
    const int* dst = ei + E;
    const size_t NF = (size_t)N * 64;

    // workspace layout
    char* p = (char*)d_ws;
    float* ACC = (float*)p; p += NF * 4;
    u16* QA = (u16*)p; p += NF * 2;           // bf16 activation buffers (5)
    u16* QB = (u16*)p; p += NF * 2;
    u16* QC = (u16*)p; p += NF * 2;
    u16* QD = (u16*)p; p += NF * 2;
    u16* QE = (u16*)p; p += NF * 2;
    int2* csr = (int2*)p; p += (size_t)E * 8;
    int* rank = (int*)p; p += (size_t)E * 4;
    int* cs   = (int*)p; p += (size_t)N * 4;          // cs + cdp contiguous
    int* cdp  = (int*)p; p += (size_t)N * 16 * 4;     // (single memset)
    float* t1 = (float*)p; p += (size_t)N * 4;
    float* t2 = (float*)p; p += (size_t)N * 4;
    float* t3 = (float*)p; p += (size_t)N * 4;
    float* t4 = (float*)p; p += (size_t)N * 4;
    float* dinv = (float*)p; p += (size_t)N * 4;
    int* rowptr = (int*)p; p += (size_t)(N + 1) * 4;
    int* bsum   = (int*)p; p += 1024 * 4;

    const int gE   = (E + TB - 1) / TB;
    const int gE4  = ((E + 3) / 4 + TB - 1) / TB;
    const int gN   = (N + TB - 1) / TB;                // scan blocks (<=1024)
    const int gN16 = (N * 16 + TB - 1) / TB;           // 16 lanes/node
    const int gNW  = (N + 3) / 4;                      // wave-per-node
    const int gNF  = (int)((NF + TB - 1) / TB);
    const int gMM  = 3200;                             // dense grid-stride

    // norm + CSR build
    hipMemsetAsync(cs, 0, (size_t)N * 17 * 4, stream);  // cs + cdp in one shot
    k_counts<<<gE, TB, 0, stream>>>(src, dst, cs, cdp, rank, E);
    k_scan_a<<<gN, TB, 0, stream>>>(cdp, rowptr, bsum, N);
    k_scan_b<<<1, 1024, 0, stream>>>(bsum, gN);
    k_scan_c<<<gN, TB, 0, stream>>>(rowptr, bsum, cs, dinv, N, E);
    k_fill<<<gE4, TB, 0, stream>>>(src, dst, rank, rowptr, dinv, csr, E);

    // --- Layer 1 (Fin=1) ---
    k_gather1<<<gN16, TB, 0, stream>>>(x,  x,  t1, rowptr, csr, 1.f,  0.f, N);
    k_gather1<<<gN16, TB, 0, stream>>>(t1, x,  t2, rowptr, csr, 2.f, -1.f, N);
    k_gather1<<<gN16, TB, 0, stream>>>(t2, t1, t3, rowptr, csr, 2.f, -1.f, N);
    k_gather1<<<gN16, TB, 0, stream>>>(t3, t2, t4, rowptr, csr, 2.f, -1.f, N);
    k_layer1<<<gNF, TB, 0, stream>>>(x, t1, t2, t3, t4, W1, b1, QA, N);

    // --- Layers 2 & 3 (Fin=64), all-bf16 activations ---
    // h=QA (stable). T1=QB, T2=QC, T3=QD, T4=QE.
    //  gT1: in=A           -> B
    //  mm01: ACC = b + A@W0 + B@W1        (A dead after gT2's prev read)
    //  gT2: in=B, prev=A   -> C
    //  gT3: in=C, prev=B   -> D
    //  gT4: in=D, prev=C   -> E
    //  mm234R: h' = relu(ACC + C@W2 + D@W3 + E@W4) -> A
    for (int layer = 0; layer < 2; ++layer) {
        const float* W = (layer == 0) ? W2 : W3;
        const float* b = (layer == 0) ? b2 : b3;
        k_gather64o<<<gNW, TB, 0, stream>>>(QA, QA, QB, rowptr, csr, 1.f,  0.f, N);
        k_matmul2<<<gMM, TB, 0, stream>>>(QA, QB, W + 0 * 4096, W + 1 * 4096, b, ACC, N);
        k_gather64o<<<gNW, TB, 0, stream>>>(QB, QA, QC, rowptr, csr, 2.f, -1.f, N);
        k_gather64o<<<gNW, TB, 0, stream>>>(QC, QB, QD, rowptr, csr, 2.f, -1.f, N);
        k_gather64o<<<gNW, TB, 0, stream>>>(QD, QC, QE, rowptr, csr, 2.f, -1.f, N);
        k_matmul3R<<<gMM, TB, 0, stream>>>(QC, QD, QE, W + 2 * 4096, W + 3 * 4096,
                                           W + 4 * 4096, ACC, QA, N);
    }

    // --- Final head: h = QA (bf16) ---
    k_final<<<gNW, TB, 0, stream>>>(QA, Wfc, bfc, out, N);
}

// Round 10
// 1070.715 us; speedup vs baseline: 3.3149x; 3.3149x over previous
//
#include <hip/hip_runtime.h>

// ChebNet: 3x ChebConv(K=5) + relu + linear head. N=100000, E=1600000, HID=64.
// R10: R8's proven dense split (mm01 / mm23 / mmR -- max TWO register-resident
// W matrices per kernel; three spills to scratch, measured 3.5GB traffic in R9)
// + R9's vectorized fill and single memset. All-bf16 activations, fp32 acc.

#define TB 256

typedef unsigned short u16;
typedef unsigned int u32;

__device__ inline u16 f2bf(float v) {            // RNE fp32 -> bf16
    unsigned u = __float_as_uint(v);
    return (u16)((u + 0x7fffu + ((u >> 16) & 1u)) >> 16);
}
__device__ inline float bflo(u32 v) { return __uint_as_float(v << 16); }
__device__ inline float bfhi(u32 v) { return __uint_as_float(v & 0xffff0000u); }
__device__ inline float bf2f(u16 v) { return __uint_as_float(((u32)v) << 16); }

// ---------- pass A: degree histograms + per-edge rank in dst bucket ----------
// At the device fabric-atomic latency*concurrency floor (~21 G atomics/s).
__global__ __launch_bounds__(TB) void k_counts(const int* __restrict__ src,
                                               const int* __restrict__ dst,
                                               int* __restrict__ cs,
                                               int* __restrict__ cdp,
                                               int* __restrict__ rank, int E) {
    int e = blockIdx.x * TB + threadIdx.x;
    if (e < E) {
        atomicAdd(&cs[src[e]], 1);
        rank[e] = atomicAdd(&cdp[(size_t)dst[e] * 16], 1);
    }
}

// ---------- CSR build ----------
__global__ __launch_bounds__(TB) void k_scan_a(const int* __restrict__ cdp,
                                               int* __restrict__ excl,
                                               int* __restrict__ bsum, int N) {
    __shared__ int s[TB];
    int t = threadIdx.x;
    int i = blockIdx.x * TB + t;
    int v = (i < N) ? cdp[(size_t)i * 16] : 0;
    s[t] = v;
    __syncthreads();
    for (int o = 1; o < TB; o <<= 1) {
        int add = (t >= o) ? s[t - o] : 0;
        __syncthreads();
        s[t] += add;
        __syncthreads();
    }
    if (i < N) excl[i] = s[t] - v;
    if (t == TB - 1) bsum[blockIdx.x] = s[t];
}

__global__ __launch_bounds__(1024) void k_scan_b(int* __restrict__ bsum, int nb) {
    __shared__ int s[1024];
    int t = threadIdx.x;
    int v = (t < nb) ? bsum[t] : 0;
    s[t] = v;
    __syncthreads();
    for (int o = 1; o < 1024; o <<= 1) {
        int add = (t >= o) ? s[t - o] : 0;
        __syncthreads();
        s[t] += add;
        __syncthreads();
    }
    if (t < nb) bsum[t] = s[t] - v;
}

__global__ __launch_bounds__(TB) void k_scan_c(int* __restrict__ rowptr,
                                               const int* __restrict__ bsum,
                                               const int* __restrict__ cs,
                                               float* __restrict__ dinv,
                                               int N, int E) {
    int i = blockIdx.x * TB + threadIdx.x;
    if (i < N) {
        rowptr[i] += bsum[blockIdx.x];
        int d = cs[i];
        dinv[i] = d > 0 ? rsqrtf((float)d) : 0.f;
    }
    if (i == 0) rowptr[N] = E;
}

// atomic-free fill, 4 edges/thread: pos = rowptr[dst] + rank
__global__ __launch_bounds__(TB) void k_fill(const int* __restrict__ src,
                                             const int* __restrict__ dst,
                                             const int* __restrict__ rank,
                                             const int* __restrict__ rowptr,
                                             const float* __restrict__ dinv,
                                             int2* __restrict__ csr, int E) {
    int t = blockIdx.x * TB + threadIdx.x;
    int e0 = t * 4;
    if (e0 + 3 < E) {
        int4 s = *(const int4*)(src + e0);
        int4 d = *(const int4*)(dst + e0);
        int4 r = *(const int4*)(rank + e0);
        csr[rowptr[d.x] + r.x] = make_int2(s.x, __float_as_int(-dinv[s.x] * dinv[d.x]));
        csr[rowptr[d.y] + r.y] = make_int2(s.y, __float_as_int(-dinv[s.y] * dinv[d.y]));
        csr[rowptr[d.z] + r.z] = make_int2(s.z, __float_as_int(-dinv[s.z] * dinv[d.z]));
        csr[rowptr[d.w] + r.w] = make_int2(s.w, __float_as_int(-dinv[s.w] * dinv[d.w]));
    } else {
        for (int e = e0; e < E; ++e) {
            int s = src[e], d = dst[e];
            csr[rowptr[d] + rank[e]] = make_int2(s, __float_as_int(-dinv[s] * dinv[d]));
        }
    }
}

// ---------- layer-1 (Fin=1) props: 16 lanes per node ----------
__global__ __launch_bounds__(TB) void k_gather1(const float* __restrict__ in,
                                                const float* __restrict__ prev,
                                                float* __restrict__ out,
                                                const int* __restrict__ rowptr,
                                                const int2* __restrict__ csr,
                                                float scale, float scale0, int N) {
    int l16 = threadIdx.x & 15;
    int n = blockIdx.x * (TB / 16) + (threadIdx.x >> 4);
    if (n >= N) return;
    int beg = rowptr[n], end = rowptr[n + 1];
    float s = 0.f;
    for (int i = beg + l16; i < end; i += 16) {
        int2 e = csr[i];
        s = fmaf(__int_as_float(e.y), in[e.x], s);
    }
    s += __shfl_down(s, 8, 16);
    s += __shfl_down(s, 4, 16);
    s += __shfl_down(s, 2, 16);
    s += __shfl_down(s, 1, 16);
    if (l16 == 0) out[n] = fmaf(scale, s, scale0 * prev[n]);
}

// Layer 1 combine: h = relu(b1 + sum_k t_k * W1[k]) -> bf16
__global__ __launch_bounds__(TB) void k_layer1(const float* __restrict__ x,
                                               const float* __restrict__ t1,
                                               const float* __restrict__ t2,
                                               const float* __restrict__ t3,
                                               const float* __restrict__ t4,
                                               const float* __restrict__ W1,
                                               const float* __restrict__ b1,
                                               u16* __restrict__ Hb, int N) {
    int tid = blockIdx.x * TB + threadIdx.x;
    if (tid >= N * 64) return;
    int n = tid >> 6, f = tid & 63;
    float v = b1[f];
    v = fmaf(x[n],  W1[f],       v);
    v = fmaf(t1[n], W1[64 + f],  v);
    v = fmaf(t2[n], W1[128 + f], v);
    v = fmaf(t3[n], W1[192 + f], v);
    v = fmaf(t4[n], W1[256 + f], v);
    Hb[tid] = f2bf(fmaxf(v, 0.f));
}

// ---------- prop: bf16 gather, 4-deep MLP (step-32, 4 slots/group) ----------
__global__ __launch_bounds__(TB) void k_gather64o(const u16* __restrict__ inb,
                                                  const u16* __restrict__ prevb,
                                                  u16* __restrict__ outB,
                                                  const int* __restrict__ rowptr,
                                                  const int2* __restrict__ csr,
                                                  float scale, float scale0, int N) {
    int lane = threadIdx.x & 63;
    int g = lane >> 3;
    int p = lane & 7;
    int n = blockIdx.x * (TB / 64) + (threadIdx.x >> 6);
    if (n >= N) return;
    int beg = rowptr[n], end = rowptr[n + 1];
    float s0 = 0.f, s1 = 0.f, s2 = 0.f, s3 = 0.f;
    float s4 = 0.f, s5 = 0.f, s6 = 0.f, s7 = 0.f;
    const u16* bp = inb + 8 * p;
    for (int i0 = beg; i0 < end; i0 += 32) {
        int ia = i0 + g, ib = ia + 8, ic = ia + 16, id = ia + 24;
        bool va = ia < end, vb = ib < end, vc = ic < end, vd = id < end;
        int2 ea = csr[va ? ia : beg];
        int2 eb = csr[vb ? ib : beg];
        int2 ec = csr[vc ? ic : beg];
        int2 ed = csr[vd ? id : beg];
        uint4 ra = *(const uint4*)(bp + (size_t)ea.x * 64);
        uint4 rb = *(const uint4*)(bp + (size_t)eb.x * 64);
        uint4 rc = *(const uint4*)(bp + (size_t)ec.x * 64);
        uint4 rd = *(const uint4*)(bp + (size_t)ed.x * 64);
        float wa = va ? __int_as_float(ea.y) : 0.f;
        float wb = vb ? __int_as_float(eb.y) : 0.f;
        float wc = vc ? __int_as_float(ec.y) : 0.f;
        float wd = vd ? __int_as_float(ed.y) : 0.f;
        s0 = fmaf(wa, bflo(ra.x), s0); s1 = fmaf(wa, bfhi(ra.x), s1);
        s2 = fmaf(wa, bflo(ra.y), s2); s3 = fmaf(wa, bfhi(ra.y), s3);
        s4 = fmaf(wa, bflo(ra.z), s4); s5 = fmaf(wa, bfhi(ra.z), s5);
        s6 = fmaf(wa, bflo(ra.w), s6); s7 = fmaf(wa, bfhi(ra.w), s7);
        s0 = fmaf(wb, bflo(rb.x), s0); s1 = fmaf(wb, bfhi(rb.x), s1);
        s2 = fmaf(wb, bflo(rb.y), s2); s3 = fmaf(wb, bfhi(rb.y), s3);
        s4 = fmaf(wb, bflo(rb.z), s4); s5 = fmaf(wb, bfhi(rb.z), s5);
        s6 = fmaf(wb, bflo(rb.w), s6); s7 = fmaf(wb, bfhi(rb.w), s7);
        s0 = fmaf(wc, bflo(rc.x), s0); s1 = fmaf(wc, bfhi(rc.x), s1);
        s2 = fmaf(wc, bflo(rc.y), s2); s3 = fmaf(wc, bfhi(rc.y), s3);
        s4 = fmaf(wc, bflo(rc.z), s4); s5 = fmaf(wc, bfhi(rc.z), s5);
        s6 = fmaf(wc, bflo(rc.w), s6); s7 = fmaf(wc, bfhi(rc.w), s7);
        s0 = fmaf(wd, bflo(rd.x), s0); s1 = fmaf(wd, bfhi(rd.x), s1);
        s2 = fmaf(wd, bflo(rd.y), s2); s3 = fmaf(wd, bfhi(rd.y), s3);
        s4 = fmaf(wd, bflo(rd.z), s4); s5 = fmaf(wd, bfhi(rd.z), s5);
        s6 = fmaf(wd, bflo(rd.w), s6); s7 = fmaf(wd, bfhi(rd.w), s7);
    }
#pragma unroll
    for (int o = 8; o < 64; o <<= 1) {
        s0 += __shfl_xor(s0, o, 64); s1 += __shfl_xor(s1, o, 64);
        s2 += __shfl_xor(s2, o, 64); s3 += __shfl_xor(s3, o, 64);
        s4 += __shfl_xor(s4, o, 64); s5 += __shfl_xor(s5, o, 64);
        s6 += __shfl_xor(s6, o, 64); s7 += __shfl_xor(s7, o, 64);
    }
    if (lane < 8) {
        size_t o = (size_t)n * 64 + 8 * p;
        float t0 = scale * s0, t1 = scale * s1, t2 = scale * s2, t3 = scale * s3;
        float t4 = scale * s4, t5 = scale * s5, t6 = scale * s6, t7 = scale * s7;
        if (scale0 != 0.f) {
            uint4 pv = *(const uint4*)(prevb + o);
            t0 = fmaf(scale0, bflo(pv.x), t0); t1 = fmaf(scale0, bfhi(pv.x), t1);
            t2 = fmaf(scale0, bflo(pv.y), t2); t3 = fmaf(scale0, bfhi(pv.y), t3);
            t4 = fmaf(scale0, bflo(pv.z), t4); t5 = fmaf(scale0, bfhi(pv.z), t5);
            t6 = fmaf(scale0, bflo(pv.w), t6); t7 = fmaf(scale0, bfhi(pv.w), t7);
        }
        uint4 b;
        b.x = ((u32)f2bf(t1) << 16) | (u32)f2bf(t0);
        b.y = ((u32)f2bf(t3) << 16) | (u32)f2bf(t2);
        b.z = ((u32)f2bf(t5) << 16) | (u32)f2bf(t4);
        b.w = ((u32)f2bf(t7) << 16) | (u32)f2bf(t6);
        *(uint4*)(outB + o) = b;
    }
}

// ---------- paired dense (bf16 inputs): acc (=|+=) [b +] QA@Wa + QB@Wb ----------
// TWO register-resident W matrices max (three spills -- measured R9).
__global__ __launch_bounds__(TB) void k_matmul2(const u16* __restrict__ QA,
                                                const u16* __restrict__ QB,
                                                const float* __restrict__ Wa,
                                                const float* __restrict__ Wb,
                                                const float* __restrict__ bias,
                                                float* __restrict__ acc,
                                                int initFlag, int N) {
    int lane = threadIdx.x & 63;
    int wid = blockIdx.x * (TB / 64) + (threadIdx.x >> 6);
    int nw = gridDim.x * (TB / 64);

    float wa[64], wb[64];
#pragma unroll
    for (int j = 0; j < 64; ++j) wa[j] = Wa[j * 64 + lane];
#pragma unroll
    for (int j = 0; j < 64; ++j) wb[j] = Wb[j * 64 + lane];
    float bv = bias[lane];

    for (int n = wid; n < N; n += nw) {
        size_t o = (size_t)n * 64;
        float a = initFlag ? bv : acc[o + lane];
        const uint4* ra = (const uint4*)(QA + o);
        const uint4* rb = (const uint4*)(QB + o);
#pragma unroll
        for (int j8 = 0; j8 < 8; ++j8) {
            uint4 r = ra[j8];
            a = fmaf(bflo(r.x), wa[8 * j8 + 0], a);
            a = fmaf(bfhi(r.x), wa[8 * j8 + 1], a);
            a = fmaf(bflo(r.y), wa[8 * j8 + 2], a);
            a = fmaf(bfhi(r.y), wa[8 * j8 + 3], a);
            a = fmaf(bflo(r.z), wa[8 * j8 + 4], a);
            a = fmaf(bfhi(r.z), wa[8 * j8 + 5], a);
            a = fmaf(bflo(r.w), wa[8 * j8 + 6], a);
            a = fmaf(bfhi(r.w), wa[8 * j8 + 7], a);
        }
#pragma unroll
        for (int j8 = 0; j8 < 8; ++j8) {
            uint4 r = rb[j8];
            a = fmaf(bflo(r.x), wb[8 * j8 + 0], a);
            a = fmaf(bfhi(r.x), wb[8 * j8 + 1], a);
            a = fmaf(bflo(r.y), wb[8 * j8 + 2], a);
            a = fmaf(bfhi(r.y), wb[8 * j8 + 3], a);
            a = fmaf(bflo(r.z), wb[8 * j8 + 4], a);
            a = fmaf(bfhi(r.z), wb[8 * j8 + 5], a);
            a = fmaf(bflo(r.w), wb[8 * j8 + 6], a);
            a = fmaf(bfhi(r.w), wb[8 * j8 + 7], a);
        }
        acc[o + lane] = a;
    }
}

// ---------- final dense of a layer: h = relu(acc + bf(Qx)@W) -> bf16 ----------
__global__ __launch_bounds__(TB) void k_matmulR(const u16* __restrict__ Qx,
                                                const float* __restrict__ W,
                                                const float* __restrict__ acc,
                                                u16* __restrict__ hB, int N) {
    int lane = threadIdx.x & 63;
    int wid = blockIdx.x * (TB / 64) + (threadIdx.x >> 6);
    int nw = gridDim.x * (TB / 64);

    float wcol[64];
#pragma unroll
    for (int j = 0; j < 64; ++j) wcol[j] = W[j * 64 + lane];

    for (int n = wid; n < N; n += nw) {
        size_t o = (size_t)n * 64;
        float a = acc[o + lane];
        const uint4* row = (const uint4*)(Qx + o);
#pragma unroll
        for (int j8 = 0; j8 < 8; ++j8) {
            uint4 r = row[j8];
            a = fmaf(bflo(r.x), wcol[8 * j8 + 0], a);
            a = fmaf(bfhi(r.x), wcol[8 * j8 + 1], a);
            a = fmaf(bflo(r.y), wcol[8 * j8 + 2], a);
            a = fmaf(bfhi(r.y), wcol[8 * j8 + 3], a);
            a = fmaf(bflo(r.z), wcol[8 * j8 + 4], a);
            a = fmaf(bfhi(r.z), wcol[8 * j8 + 5], a);
            a = fmaf(bflo(r.w), wcol[8 * j8 + 6], a);
            a = fmaf(bfhi(r.w), wcol[8 * j8 + 7], a);
        }
        hB[o + lane] = f2bf(fmaxf(a, 0.f));
    }
}

// ---------- final head: out = bfc + h @ Wfc (h bf16) ----------
__global__ __launch_bounds__(TB) void k_final(const u16* __restrict__ A,
                                              const float* __restrict__ Wfc,
                                              const float* __restrict__ bfc,
                                              float* __restrict__ out, int N) {
    int lane = threadIdx.x & 63;
    int wid = blockIdx.x * (TB / 64) + (threadIdx.x >> 6);
    if (wid >= N) return;
    float v = bf2f(A[(size_t)wid * 64 + lane]) * Wfc[lane];
#pragma unroll
    for (int o = 32; o > 0; o >>= 1) v += __shfl_down(v, o, 64);
    if (lane == 0) out[wid] = v + bfc[0];
}

extern "C" void kernel_launch(void* const* d_in, const int* in_sizes, int n_in,
                              void* d_out, int out_size, void* d_ws, size_t ws_size,
                              hipStream_t stream) {
    const float* x   = (const float*)d_in[0];
    const int*   ei  = (const int*)d_in[1];
    const float* W1  = (const float*)d_in[2];
    const float* b1  = (const float*)d_in[3];
    const float* W2  = (const float*)d_in[4];
    const float* b2  = (const float*)d_in[5];
    const float* W3  = (const float*)d_in[6];
    const float* b3  = (const float*)d_in[7];
    const float* Wfc = (const float*)d_in[8];
    const float* bfc = (const float*)d_in[9];
    float* out = (float*)d_out;

    const int N = in_sizes[0];
    const int E = in_sizes[1] / 2;
    const int* src = ei;
    const int* dst = ei + E;
    const size_t NF = (size_t)N * 64;

    // workspace layout
    char* p = (char*)d_ws;
    float* ACC = (float*)p; p += NF * 4;
    u16* QA = (u16*)p; p += NF * 2;           // bf16 activation buffers (5)
    u16* QB = (u16*)p; p += NF * 2;
    u16* QC = (u16*)p; p += NF * 2;
    u16* QD = (u16*)p; p += NF * 2;
    u16* QE = (u16*)p; p += NF * 2;
    int2* csr = (int2*)p; p += (size_t)E * 8;
    int* rank = (int*)p; p += (size_t)E * 4;
    int* cs   = (int*)p; p += (size_t)N * 4;          // cs + cdp contiguous
    int* cdp  = (int*)p; p += (size_t)N * 16 * 4;     // (single memset)
    float* t1 = (float*)p; p += (size_t)N * 4;
    float* t2 = (float*)p; p += (size_t)N * 4;
    float* t3 = (float*)p; p += (size_t)N * 4;
    float* t4 = (float*)p; p += (size_t)N * 4;
    float* dinv = (float*)p; p += (size_t)N * 4;
    int* rowptr = (int*)p; p += (size_t)(N + 1) * 4;
    int* bsum   = (int*)p; p += 1024 * 4;

    const int gE   = (E + TB - 1) / TB;
    const int gE4  = ((E + 3) / 4 + TB - 1) / TB;
    const int gN   = (N + TB - 1) / TB;                // scan blocks (<=1024)
    const int gN16 = (N * 16 + TB - 1) / TB;           // 16 lanes/node
    const int gNW  = (N + 3) / 4;                      // wave-per-node
    const int gNF  = (int)((NF + TB - 1) / TB);
    const int gMM  = 3200;                             // dense grid-stride

    // norm + CSR build
    hipMemsetAsync(cs, 0, (size_t)N * 17 * 4, stream);  // cs + cdp in one shot
    k_counts<<<gE, TB, 0, stream>>>(src, dst, cs, cdp, rank, E);
    k_scan_a<<<gN, TB, 0, stream>>>(cdp, rowptr, bsum, N);
    k_scan_b<<<1, 1024, 0, stream>>>(bsum, gN);
    k_scan_c<<<gN, TB, 0, stream>>>(rowptr, bsum, cs, dinv, N, E);
    k_fill<<<gE4, TB, 0, stream>>>(src, dst, rank, rowptr, dinv, csr, E);

    // --- Layer 1 (Fin=1) ---
    k_gather1<<<gN16, TB, 0, stream>>>(x,  x,  t1, rowptr, csr, 1.f,  0.f, N);
    k_gather1<<<gN16, TB, 0, stream>>>(t1, x,  t2, rowptr, csr, 2.f, -1.f, N);
    k_gather1<<<gN16, TB, 0, stream>>>(t2, t1, t3, rowptr, csr, 2.f, -1.f, N);
    k_gather1<<<gN16, TB, 0, stream>>>(t3, t2, t4, rowptr, csr, 2.f, -1.f, N);
    k_layer1<<<gNF, TB, 0, stream>>>(x, t1, t2, t3, t4, W1, b1, QA, N);

    // --- Layers 2 & 3 (Fin=64), all-bf16 activations ---
    // h=QA. T1=QB, T2=QC, T3=QD, T4=QE.
    //  gT1: in=A           -> B
    //  mm01: ACC = b + A@W0 + B@W1
    //  gT2: in=B, prev=A   -> C
    //  gT3: in=C, prev=B   -> D
    //  mm23: ACC += C@W2 + D@W3
    //  gT4: in=D, prev=C   -> E
    //  mmR: h' = relu(ACC + E@W4) -> A
    for (int layer = 0; layer < 2; ++layer) {
        const float* W = (layer == 0) ? W2 : W3;
        const float* b = (layer == 0) ? b2 : b3;
        k_gather64o<<<gNW, TB, 0, stream>>>(QA, QA, QB, rowptr, csr, 1.f,  0.f, N);
        k_matmul2<<<gMM, TB, 0, stream>>>(QA, QB, W + 0 * 4096, W + 1 * 4096, b, ACC, 1, N);
        k_gather64o<<<gNW, TB, 0, stream>>>(QB, QA, QC, rowptr, csr, 2.f, -1.f, N);
        k_gather64o<<<gNW, TB, 0, stream>>>(QC, QB, QD, rowptr, csr, 2.f, -1.f, N);
        k_matmul2<<<gMM, TB, 0, stream>>>(QC, QD, W + 2 * 4096, W + 3 * 4096, b, ACC, 0, N);
        k_gather64o<<<gNW, TB, 0, stream>>>(QD, QC, QE, rowptr, csr, 2.f, -1.f, N);
        k_matmulR<<<gMM, TB, 0, stream>>>(QE, W + 4 * 4096, ACC, QA, N);
    }

    // --- Final head: h = QA (bf16) ---
    k_final<<<gNW, TB, 0, stream>>>(QA, Wfc, bfc, out, N);
}